// Round 5
// baseline (51.569 us; speedup 1.0000x reference)
//
#include <hip/hip_runtime.h>
#include <stdint.h>

#define NB   32768
#define NIN  64
#define NOUT 32
// ws layout (bytes)
#define OFF_PMIN 0          // 256*64*4 = 65536
#define OFF_PMAX 65536      // 65536
#define OFF_FEAT 131072     // 64*12*4 = 3072
#define OFF_EB   134144     // 32*4 = 128
#define OFF_CSW  134272     // 3072*32*2 = 196608 (16B aligned)

typedef __bf16 bf16x8 __attribute__((ext_vector_type(8)));
typedef float  f32x4  __attribute__((ext_vector_type(4)));

__device__ __forceinline__ float softplus_f(float x) {
  return fmaxf(x, 0.0f) + log1pf(expf(-fabsf(x)));
}
__device__ __forceinline__ unsigned short f2bf(float f) {
  unsigned int u = __float_as_uint(f);
  u = (u + 0x7FFFu + ((u >> 16) & 1u)) >> 16;
  return (unsigned short)u;
}

// ---------------- pass 1: per-feature min/max partials (float4, 256 blocks) ----------------
__global__ __launch_bounds__(256) void k_minmax(const float* __restrict__ X,
                                                float* __restrict__ pmin,
                                                float* __restrict__ pmax) {
  const float4* X4 = (const float4*)X;
  int t = threadIdx.x;
  int g = t & 15, r = t >> 4;
  float4 lo = {3.402823466e38f, 3.402823466e38f, 3.402823466e38f, 3.402823466e38f};
  float4 hi = {-3.402823466e38f, -3.402823466e38f, -3.402823466e38f, -3.402823466e38f};
  int base = blockIdx.x * 2048;  // 128 rows * 16 f4
  #pragma unroll
  for (int k = 0; k < 8; ++k) {
    float4 v = X4[base + k * 256 + t];
    lo.x = fminf(lo.x, v.x); lo.y = fminf(lo.y, v.y);
    lo.z = fminf(lo.z, v.z); lo.w = fminf(lo.w, v.w);
    hi.x = fmaxf(hi.x, v.x); hi.y = fmaxf(hi.y, v.y);
    hi.z = fmaxf(hi.z, v.z); hi.w = fmaxf(hi.w, v.w);
  }
  __shared__ float4 slo[16][16], shi[16][16];
  slo[r][g] = lo; shi[r][g] = hi;
  __syncthreads();
  if (t < 64) {
    int gg = t >> 2, c = t & 3;
    float l = 3.402823466e38f, h = -3.402823466e38f;
    #pragma unroll
    for (int rr = 0; rr < 16; ++rr) {
      const float* pl = (const float*)&slo[rr][gg];
      const float* ph = (const float*)&shi[rr][gg];
      l = fminf(l, pl[c]); h = fmaxf(h, ph[c]);
    }
    pmin[blockIdx.x * 64 + t] = l;
    pmax[blockIdx.x * 64 + t] = h;
  }
}

// ---------------- pass 2: fused setup: blocks 0-7 = coef, block 8 = feat params ----------------
// k-permutation: feature i -> (w=i>>4, kg=(i>>2)&3, c=i&3); element k -> (s=k>>3, j=k&7)
// frag unit index (bf16x8 units): ((w*24 + c*6 + s)*4 + kg)*32 + o, elem j.
__global__ __launch_bounds__(256) void k_setup(const float* __restrict__ pmin,
                                               const float* __restrict__ pmax,
                                               const float* __restrict__ wscale,
                                               const float* __restrict__ wshift,
                                               const float* __restrict__ alpha,
                                               const float* __restrict__ bias,
                                               const float* __restrict__ base_v,
                                               const float* __restrict__ base_g,
                                               const float* __restrict__ bsp,
                                               const float* __restrict__ tay,
                                               const float* __restrict__ jac,
                                               const float* __restrict__ che,
                                               const float* __restrict__ fou,
                                               const float* __restrict__ wav,
                                               const float* __restrict__ gains,
                                               const float* __restrict__ beta,
                                               const float* __restrict__ mixl,
                                               float* __restrict__ featp,
                                               float* __restrict__ ebias,
                                               unsigned short* __restrict__ Csw) {
  int t = threadIdx.x;
  if (blockIdx.x < 8) {
    // ---- coef: fold everything into Csw, B-fragment pre-swizzled ----
    int o = blockIdx.x * 4 + (t >> 6);
    int i = t & 63;
    int p = o * 64 + i;
    float spa = softplus_f(alpha[0]);
    float spb = softplus_f(beta[0]);
    float spg[6];
    #pragma unroll
    for (int f = 0; f < 6; ++f) spg[f] = softplus_f(gains[f]);
    float m[6], mmax = -3.402823466e38f;
    #pragma unroll
    for (int f = 0; f < 6; ++f) { m[f] = mixl[p * 6 + f] * 0.5f; mmax = fmaxf(mmax, m[f]); }
    float es = 0.f;
    #pragma unroll
    for (int f = 0; f < 6; ++f) { m[f] = __expf(m[f] - mmax); es += m[f]; }
    float inv = 1.0f / es;

    float vv = base_v[p];
    float s2 = vv * vv;
    #pragma unroll
    for (int d = 1; d < 64; d <<= 1) s2 += __shfl_xor(s2, d);
    float vn = sqrtf(s2);

    float slot[48];
    slot[0] = spa * base_g[o] * vv / vn;   // identity path: sp(alpha)*W[o,i]
    float w;
    w = spb * spg[0] * m[0] * inv;
    #pragma unroll
    for (int k = 0; k < 11; ++k) slot[1 + k] = w * bsp[p * 11 + k];
    w = spb * spg[1] * m[1] * inv;
    #pragma unroll
    for (int k = 0; k < 4; ++k)  slot[12 + k] = w * tay[p * 4 + k];
    w = spb * spg[2] * m[2] * inv;
    #pragma unroll
    for (int k = 0; k < 5; ++k)  slot[16 + k] = w * jac[p * 5 + k];
    w = spb * spg[3] * m[3] * inv;
    #pragma unroll
    for (int k = 0; k < 5; ++k)  slot[21 + k] = w * che[p * 5 + k];
    w = spb * spg[4] * m[4] * inv;
    #pragma unroll
    for (int k = 0; k < 16; ++k) slot[26 + k] = w * fou[p * 16 + k];
    w = spb * spg[5] * m[5] * inv;
    #pragma unroll
    for (int k = 0; k < 4; ++k)  slot[42 + k] = w * wav[p * 4 + k];
    slot[46] = 0.f; slot[47] = 0.f;

    // vectorized scatter: 6 x bf16x8 coalesced stores
    int wv = i >> 4, kgi = (i >> 2) & 3, cc = i & 3;
    bf16x8* CBo = reinterpret_cast<bf16x8*>(Csw);
    #pragma unroll
    for (int s = 0; s < 6; ++s) {
      bf16x8 pk;
      #pragma unroll
      for (int j = 0; j < 8; ++j) pk[j] = (__bf16)slot[s * 8 + j];
      int st = wv * 24 + cc * 6 + s;
      CBo[(st * 4 + kgi) * 32 + o] = pk;
    }
  } else {
    // ---- feat: final min/max reduce + per-feature params ----
    __shared__ float slo[4][64], shi[4][64];
    int i = t & 63, cg = t >> 6;
    float lo = 3.402823466e38f, hi = -3.402823466e38f;
    for (int p = cg; p < 256; p += 4) {
      lo = fminf(lo, pmin[p * 64 + i]);
      hi = fmaxf(hi, pmax[p * 64 + i]);
    }
    slo[cg][i] = lo; shi[cg][i] = hi;
    __syncthreads();
    if (t < 64) {
      lo = fminf(fminf(slo[0][t], slo[1][t]), fminf(slo[2][t], slo[3][t]));
      hi = fmaxf(fmaxf(shi[0][t], shi[1][t]), fmaxf(shi[2][t], shi[3][t]));
      if (hi - lo < 1e-8f) { lo = lo - 0.5f; hi = hi + 0.5f; }
      float d = hi - lo;
      float* fp = featp + t * 12;
      fp[0] = lo;
      fp[1] = 8.0f / d;   // u = (x-lo)*ih maps grid to integers 0..8
      #pragma unroll
      for (int c = 0; c < 4; ++c) {
        float a = softplus_f(wscale[t * 4 + c]) + 1e-6f;
        fp[2 + c] = 1.0f / a;
        fp[6 + c] = wshift[t * 4 + c];
      }
      fp[10] = 0.f; fp[11] = 0.f;
    }
    if (t >= 128 && t < 160) {
      int o = t - 128;
      ebias[o] = softplus_f(alpha[0]) * bias[o];
    }
  }
}

// ---------------- pass 3: main fused kernel (zero-LDS main loop) ----------------
// 256 threads = 4 waves, one 16-sample tile, K-split 4 ways. Wave w owns features
// [w*16, w*16+16). Lane (col,kg) computes feature w*16+kg*4+c for sample col in
// pass c; the k-permutation makes its 48 values exactly its own A-fragments.
__global__ __launch_bounds__(256, 4) void k_main(const float* __restrict__ X,
                                                 const unsigned short* __restrict__ Csw,
                                                 const float* __restrict__ featp,
                                                 const float* __restrict__ ebias,
                                                 float* __restrict__ out) {
  __shared__ float red[3][512];

  int t = threadIdx.x;
  int w = t >> 6, lane = t & 63;
  int col = lane & 15, kg = lane >> 4;
  int sbase = blockIdx.x * 16;

  // one float4 load: x for this lane's 4 passes (features w*16 + kg*4 + {0..3})
  const float4* X4 = (const float4*)X;
  float4 xq = X4[(sbase + col) * 16 + w * 4 + kg];
  float xr[4] = {xq.x, xq.y, xq.z, xq.w};

  f32x4 acc0 = {0.f, 0.f, 0.f, 0.f};
  f32x4 acc1 = {0.f, 0.f, 0.f, 0.f};
  const bf16x8* CB = reinterpret_cast<const bf16x8*>(Csw);
  const bf16x8* CBw = CB + (size_t)w * 3072 + kg * 32;

  bf16x8 B0, B1, B2, B3, B4, B5, B6, B7, B8, B9, B10, B11;
#define LOADB(cc) do { const bf16x8* p_ = CBw + (size_t)(cc) * 768;            \
    B0 = p_[col];        B1 = p_[col + 16];                                    \
    B2 = p_[128 + col];  B3 = p_[128 + col + 16];                              \
    B4 = p_[256 + col];  B5 = p_[256 + col + 16];                              \
    B6 = p_[384 + col];  B7 = p_[384 + col + 16];                              \
    B8 = p_[512 + col];  B9 = p_[512 + col + 16];                              \
    B10 = p_[640 + col]; B11 = p_[640 + col + 16]; } while (0)

  LOADB(0);

  #pragma unroll 1
  for (int c = 0; c < 4; ++c) {
    int f = w * 16 + kg * 4 + c;
    const float4* fq = (const float4*)(featp + f * 12);
    float4 q0 = fq[0];   // xmin, ih, inva0, inva1
    float4 q1 = fq[1];   // inva2, inva3, shift0, shift1
    float4 q2 = fq[2];   // shift2, shift3, -, -
    float x = xr[c];

    bf16x8 A0, A1, A2, A3, A4, A5;
    A0[0] = (__bf16)x;                       // k0: identity

    // ---- B-spline, normalized coords: u in [0,8], integer knots ----
    {
      float u = (x - q0.x) * q0.y;
      int ji = (int)u;
      float e0 = (ji == 0) ? 1.f : 0.f;
      float e1 = (ji == 1) ? 1.f : 0.f;
      float e2 = (ji == 2) ? 1.f : 0.f;
      float e3 = (ji == 3) ? 1.f : 0.f;
      float e4 = (ji == 4) ? 1.f : 0.f;
      float e5 = (ji == 5) ? 1.f : 0.f;
      float e6 = (ji == 6) ? 1.f : 0.f;
      float e7 = (ji == 7) ? 1.f : 0.f;
      float d0 = u,       d1 = u - 1.f, d2 = u - 2.f, d3 = u - 3.f, d4 = u - 4.f;
      float d5 = u - 5.f, d6 = u - 6.f, d7 = u - 7.f, d8 = u - 8.f;
      float a2 = -d1 * e0;
      float a3 = d0 * e0 - d2 * e1;
      float a4 = d1 * e1 - d3 * e2;
      float a5 = d2 * e2 - d4 * e3;
      float a6 = d3 * e3 - d5 * e4;
      float a7 = d4 * e4 - d6 * e5;
      float a8 = d5 * e5 - d7 * e6;
      float a9 = d6 * e6 - d8 * e7;
      float a10 = d7 * e7;
      float h0 = 0.5f * d0, h2 = 0.5f * d2, h3 = 0.5f * d3, h4 = 0.5f * d4;
      float h1 = 0.5f * d1, h5 = 0.5f * d5, h6 = 0.5f * d6, h7 = 0.5f * d7, h8 = 0.5f * d8;
      float c1v = -d1 * a2;
      float c2v = d0 * a2 - h2 * a3;
      float c3v = h0 * a3 - h3 * a4;
      float c4v = h1 * a4 - h4 * a5;
      float c5v = h2 * a5 - h5 * a6;
      float c6v = h3 * a6 - h6 * a7;
      float c7v = h4 * a7 - h7 * a8;
      float c8v = h5 * a8 - h8 * a9;
      float c9v = h6 * a9 - d8 * a10;
      float c10v = d7 * a10;
      const float TH = 0.33333333333333f;
      A0[1] = (__bf16)(-d1 * c1v);
      A0[2] = (__bf16)(d0 * c1v - h2 * c2v);
      A0[3] = (__bf16)(h0 * c2v - TH * (d3 * c3v));
      A0[4] = (__bf16)((d0 * c3v - d4 * c4v) * TH);
      A0[5] = (__bf16)((d1 * c4v - d5 * c5v) * TH);
      A0[6] = (__bf16)((d2 * c5v - d6 * c6v) * TH);
      A0[7] = (__bf16)((d3 * c6v - d7 * c7v) * TH);
      A1[0] = (__bf16)((d4 * c7v - d8 * c8v) * TH);
      A1[1] = (__bf16)(TH * (d5 * c8v) - h8 * c9v);
      A1[2] = (__bf16)(h6 * c9v - d8 * c10v);
      A1[3] = (__bf16)(d7 * c10v);
    }
    // ---- Taylor (k12-15) ----
    {
      float x2 = x * x;
      A1[4] = (__bf16)1.0f;
      A1[5] = (__bf16)x;
      A1[6] = (__bf16)(x2 * 0.5f);
      A1[7] = (__bf16)(x2 * x * (1.0f / 6.0f));
    }
    // ---- Jacobi (k16-20) ----
    {
      float j1 = 1.41421356237f * x;
      float j2 = (1.5f * x * j1 - 0.6f) * 0.57735026919f;
      float j3 = (1.6f * x * j2 - 0.685714285714f * j1) * 0.5f;
      float j4 = (1.66666666667f * x * j3 - 0.740740740741f * j2) * 0.44721359550f;
      A2[0] = (__bf16)1.0f;
      A2[1] = (__bf16)j1;
      A2[2] = (__bf16)j2;
      A2[3] = (__bf16)j3;
      A2[4] = (__bf16)j4;
    }
    // ---- Chebyshev (k21-25) ----
    {
      float xc = fminf(fmaxf(x, -1e6f), 1e6f);
      float cc2 = 2.0f * xc * xc - 1.0f;
      float cc3 = 2.0f * xc * cc2 - xc;
      float cc4 = 2.0f * xc * cc3 - cc2;
      A2[5] = (__bf16)1.0f;
      A2[6] = (__bf16)(xc * 0.70710678119f);
      A2[7] = (__bf16)(cc2 * 0.57735026919f);
      A3[0] = (__bf16)(cc3 * 0.5f);
      A3[1] = (__bf16)(cc4 * 0.44721359550f);
    }
    // ---- Fourier (k26-41): cos k26-33, sin k34-41 ----
    {
      float s1 = __sinf(x), c1f = __cosf(x);
      float cf[8], sf[8];
      cf[0] = c1f; sf[0] = s1;
      #pragma unroll
      for (int k = 1; k < 8; ++k) {
        cf[k] = cf[k - 1] * c1f - sf[k - 1] * s1;
        sf[k] = sf[k - 1] * c1f + cf[k - 1] * s1;
      }
      A3[2] = (__bf16)(cf[0] * 0.25f);
      A3[3] = (__bf16)(cf[1] * 0.25f);
      A3[4] = (__bf16)(cf[2] * 0.25f);
      A3[5] = (__bf16)(cf[3] * 0.25f);
      A3[6] = (__bf16)(cf[4] * 0.25f);
      A3[7] = (__bf16)(cf[5] * 0.25f);
      A4[0] = (__bf16)(cf[6] * 0.25f);
      A4[1] = (__bf16)(cf[7] * 0.25f);
      A4[2] = (__bf16)(sf[0] * 0.25f);
      A4[3] = (__bf16)(sf[1] * 0.25f);
      A4[4] = (__bf16)(sf[2] * 0.25f);
      A4[5] = (__bf16)(sf[3] * 0.25f);
      A4[6] = (__bf16)(sf[4] * 0.25f);
      A4[7] = (__bf16)(sf[5] * 0.25f);
      A5[0] = (__bf16)(sf[6] * 0.25f);
      A5[1] = (__bf16)(sf[7] * 0.25f);
    }
    // ---- Wavelet (k42-45) + pad (k46-47) ----
    {
      float u0 = (x - q1.z) * q0.z, u1 = (x - q1.w) * q0.w;
      float u2 = (x - q2.x) * q1.x, u3 = (x - q2.y) * q1.y;
      float s0 = u0 * u0, s1w = u1 * u1, s2w = u2 * u2, s3 = u3 * u3;
      A5[2] = (__bf16)((s0 - 1.0f) * __expf(-0.5f * s0));
      A5[3] = (__bf16)((s1w - 1.0f) * __expf(-0.5f * s1w));
      A5[4] = (__bf16)((s2w - 1.0f) * __expf(-0.5f * s2w));
      A5[5] = (__bf16)((s3 - 1.0f) * __expf(-0.5f * s3));
      A5[6] = (__bf16)0.0f;
      A5[7] = (__bf16)0.0f;
    }

    // ---- MFMA: 6 K-steps, A and B both from registers; no LDS, no barriers ----
    acc0 = __builtin_amdgcn_mfma_f32_16x16x32_bf16(A0, B0, acc0, 0, 0, 0);
    acc1 = __builtin_amdgcn_mfma_f32_16x16x32_bf16(A0, B1, acc1, 0, 0, 0);
    acc0 = __builtin_amdgcn_mfma_f32_16x16x32_bf16(A1, B2, acc0, 0, 0, 0);
    acc1 = __builtin_amdgcn_mfma_f32_16x16x32_bf16(A1, B3, acc1, 0, 0, 0);
    acc0 = __builtin_amdgcn_mfma_f32_16x16x32_bf16(A2, B4, acc0, 0, 0, 0);
    acc1 = __builtin_amdgcn_mfma_f32_16x16x32_bf16(A2, B5, acc1, 0, 0, 0);
    acc0 = __builtin_amdgcn_mfma_f32_16x16x32_bf16(A3, B6, acc0, 0, 0, 0);
    acc1 = __builtin_amdgcn_mfma_f32_16x16x32_bf16(A3, B7, acc1, 0, 0, 0);
    acc0 = __builtin_amdgcn_mfma_f32_16x16x32_bf16(A4, B8, acc0, 0, 0, 0);
    acc1 = __builtin_amdgcn_mfma_f32_16x16x32_bf16(A4, B9, acc1, 0, 0, 0);
    acc0 = __builtin_amdgcn_mfma_f32_16x16x32_bf16(A5, B10, acc0, 0, 0, 0);
    acc1 = __builtin_amdgcn_mfma_f32_16x16x32_bf16(A5, B11, acc1, 0, 0, 0);

    if (c < 3) LOADB(c + 1);
  }
#undef LOADB

  // ---- 4-way cross-wave K-reduction (single barrier) ----
  if (w > 0) {
    float* rw = &red[w - 1][0];
    #pragma unroll
    for (int j = 0; j < 4; ++j) {
      rw[(kg * 4 + j) * 32 + col]      = acc0[j];
      rw[(kg * 4 + j) * 32 + col + 16] = acc1[j];
    }
  }
  __syncthreads();
  if (w == 0) {
    float eb0 = ebias[col], eb1 = ebias[col + 16];
    #pragma unroll
    for (int j = 0; j < 4; ++j) {
      int idx0 = (kg * 4 + j) * 32 + col;
      int idx1 = idx0 + 16;
      int row = sbase + kg * 4 + j;
      out[row * 32 + col]      = acc0[j] + red[0][idx0] + red[1][idx0] + red[2][idx0] + eb0;
      out[row * 32 + col + 16] = acc1[j] + red[0][idx1] + red[1][idx1] + red[2][idx1] + eb1;
    }
  }
}

extern "C" void kernel_launch(void* const* d_in, const int* in_sizes, int n_in,
                              void* d_out, int out_size, void* d_ws, size_t ws_size,
                              hipStream_t stream) {
  const float* X   = (const float*)d_in[0];
  const float* bv  = (const float*)d_in[1];
  const float* bg  = (const float*)d_in[2];
  const float* bbi = (const float*)d_in[3];
  const float* bsp = (const float*)d_in[4];
  const float* tay = (const float*)d_in[5];
  const float* jac = (const float*)d_in[6];
  const float* che = (const float*)d_in[7];
  const float* fou = (const float*)d_in[8];
  const float* wav = (const float*)d_in[9];
  const float* wsc = (const float*)d_in[10];
  const float* wsh = (const float*)d_in[11];
  const float* gns = (const float*)d_in[12];
  const float* alp = (const float*)d_in[13];
  const float* bet = (const float*)d_in[14];
  const float* mxl = (const float*)d_in[15];
  float* out = (float*)d_out;

  uint8_t* w = (uint8_t*)d_ws;
  float* pmin  = (float*)(w + OFF_PMIN);
  float* pmax  = (float*)(w + OFF_PMAX);
  float* featp = (float*)(w + OFF_FEAT);
  float* ebias = (float*)(w + OFF_EB);
  unsigned short* Csw = (unsigned short*)(w + OFF_CSW);

  k_minmax<<<256, 256, 0, stream>>>(X, pmin, pmax);
  k_setup<<<9, 256, 0, stream>>>(pmin, pmax, wsc, wsh, alp, bbi,
                                 bv, bg, bsp, tay, jac, che, fou, wav,
                                 gns, bet, mxl, featp, ebias, Csw);
  k_main<<<2048, 256, 0, stream>>>(X, Csw, featp, ebias, out);
}

// Round 6
// 38.972 us; speedup vs baseline: 1.3232x; 1.3232x over previous
//
#include <hip/hip_runtime.h>
#include <stdint.h>

#define NB   32768
#define NIN  64
#define NOUT 32
// ws layout (bytes)
#define OFF_PMIN 0          // 64*64*4 = 16384
#define OFF_PMAX 16384      // 16384
#define OFF_FEAT 32768      // 64*12*4 = 3072
#define OFF_EB   35840      // 32*4 = 128
#define OFF_CSW  35968      // 3072*32*2 = 196608 (16B aligned)

typedef __bf16 bf16x8 __attribute__((ext_vector_type(8)));
typedef float  f32x4  __attribute__((ext_vector_type(4)));

__device__ __forceinline__ float softplus_f(float x) {
  return fmaxf(x, 0.0f) + log1pf(expf(-fabsf(x)));
}

// ---------------- pass 1: per-feature min/max partials (float4, 64 blocks) ----------------
__global__ __launch_bounds__(256) void k_minmax(const float* __restrict__ X,
                                                float* __restrict__ pmin,
                                                float* __restrict__ pmax) {
  const float4* X4 = (const float4*)X;
  int t = threadIdx.x;
  int g = t & 15, r = t >> 4;
  float4 lo = {3.402823466e38f, 3.402823466e38f, 3.402823466e38f, 3.402823466e38f};
  float4 hi = {-3.402823466e38f, -3.402823466e38f, -3.402823466e38f, -3.402823466e38f};
  int base = blockIdx.x * 8192;  // 512 rows * 16 f4
  #pragma unroll 8
  for (int k = 0; k < 32; ++k) {
    float4 v = X4[base + k * 256 + t];
    lo.x = fminf(lo.x, v.x); lo.y = fminf(lo.y, v.y);
    lo.z = fminf(lo.z, v.z); lo.w = fminf(lo.w, v.w);
    hi.x = fmaxf(hi.x, v.x); hi.y = fmaxf(hi.y, v.y);
    hi.z = fmaxf(hi.z, v.z); hi.w = fmaxf(hi.w, v.w);
  }
  __shared__ float4 slo[16][16], shi[16][16];
  slo[r][g] = lo; shi[r][g] = hi;
  __syncthreads();
  if (t < 64) {
    int gg = t >> 2, c = t & 3;
    float l = 3.402823466e38f, h = -3.402823466e38f;
    #pragma unroll
    for (int rr = 0; rr < 16; ++rr) {
      const float* pl = (const float*)&slo[rr][gg];
      const float* ph = (const float*)&shi[rr][gg];
      l = fminf(l, pl[c]); h = fmaxf(h, ph[c]);
    }
    pmin[blockIdx.x * 64 + t] = l;
    pmax[blockIdx.x * 64 + t] = h;
  }
}

// ---------------- pass 2: fused setup: blocks 0-7 = coef, block 8 = feat params ----------------
// k-permutation: feature i -> (w=i>>4, kg=(i>>2)&3, c=i&3); element k -> (s=k>>3, j=k&7)
// frag unit index (bf16x8 units): ((w*24 + c*6 + s)*4 + kg)*32 + o, elem j.
__global__ __launch_bounds__(256) void k_setup(const float* __restrict__ pmin,
                                               const float* __restrict__ pmax,
                                               const float* __restrict__ wscale,
                                               const float* __restrict__ wshift,
                                               const float* __restrict__ alpha,
                                               const float* __restrict__ bias,
                                               const float* __restrict__ base_v,
                                               const float* __restrict__ base_g,
                                               const float* __restrict__ bsp,
                                               const float* __restrict__ tay,
                                               const float* __restrict__ jac,
                                               const float* __restrict__ che,
                                               const float* __restrict__ fou,
                                               const float* __restrict__ wav,
                                               const float* __restrict__ gains,
                                               const float* __restrict__ beta,
                                               const float* __restrict__ mixl,
                                               float* __restrict__ featp,
                                               float* __restrict__ ebias,
                                               unsigned short* __restrict__ Csw) {
  int t = threadIdx.x;
  if (blockIdx.x < 8) {
    // ---- coef: fold everything into Csw, B-fragment pre-swizzled ----
    int o = blockIdx.x * 4 + (t >> 6);
    int i = t & 63;
    int p = o * 64 + i;
    float spa = softplus_f(alpha[0]);
    float spb = softplus_f(beta[0]);
    float spg[6];
    #pragma unroll
    for (int f = 0; f < 6; ++f) spg[f] = softplus_f(gains[f]);
    float m[6], mmax = -3.402823466e38f;
    #pragma unroll
    for (int f = 0; f < 6; ++f) { m[f] = mixl[p * 6 + f] * 0.5f; mmax = fmaxf(mmax, m[f]); }
    float es = 0.f;
    #pragma unroll
    for (int f = 0; f < 6; ++f) { m[f] = __expf(m[f] - mmax); es += m[f]; }
    float inv = 1.0f / es;

    float vv = base_v[p];
    float s2 = vv * vv;
    #pragma unroll
    for (int d = 1; d < 64; d <<= 1) s2 += __shfl_xor(s2, d);
    float vn = sqrtf(s2);

    float slot[48];
    slot[0] = spa * base_g[o] * vv / vn;   // identity path: sp(alpha)*W[o,i]
    float w;
    w = spb * spg[0] * m[0] * inv;
    #pragma unroll
    for (int k = 0; k < 11; ++k) slot[1 + k] = w * bsp[p * 11 + k];
    w = spb * spg[1] * m[1] * inv;
    #pragma unroll
    for (int k = 0; k < 4; ++k)  slot[12 + k] = w * tay[p * 4 + k];
    w = spb * spg[2] * m[2] * inv;
    #pragma unroll
    for (int k = 0; k < 5; ++k)  slot[16 + k] = w * jac[p * 5 + k];
    w = spb * spg[3] * m[3] * inv;
    #pragma unroll
    for (int k = 0; k < 5; ++k)  slot[21 + k] = w * che[p * 5 + k];
    w = spb * spg[4] * m[4] * inv;
    #pragma unroll
    for (int k = 0; k < 16; ++k) slot[26 + k] = w * fou[p * 16 + k];
    w = spb * spg[5] * m[5] * inv;
    #pragma unroll
    for (int k = 0; k < 4; ++k)  slot[42 + k] = w * wav[p * 4 + k];
    slot[46] = 0.f; slot[47] = 0.f;

    // vectorized scatter: 6 x bf16x8 coalesced stores
    int wv = i >> 4, kgi = (i >> 2) & 3, cc = i & 3;
    bf16x8* CBo = reinterpret_cast<bf16x8*>(Csw);
    #pragma unroll
    for (int s = 0; s < 6; ++s) {
      bf16x8 pk;
      #pragma unroll
      for (int j = 0; j < 8; ++j) pk[j] = (__bf16)slot[s * 8 + j];
      int st = wv * 24 + cc * 6 + s;
      CBo[(st * 4 + kgi) * 32 + o] = pk;
    }
  } else {
    // ---- feat: final min/max reduce + per-feature params ----
    __shared__ float slo[4][64], shi[4][64];
    int i = t & 63, cg = t >> 6;
    float lo = 3.402823466e38f, hi = -3.402823466e38f;
    #pragma unroll
    for (int pp = 0; pp < 16; ++pp) {
      int p = pp * 4 + cg;
      lo = fminf(lo, pmin[p * 64 + i]);
      hi = fmaxf(hi, pmax[p * 64 + i]);
    }
    slo[cg][i] = lo; shi[cg][i] = hi;
    __syncthreads();
    if (t < 64) {
      lo = fminf(fminf(slo[0][t], slo[1][t]), fminf(slo[2][t], slo[3][t]));
      hi = fmaxf(fmaxf(shi[0][t], shi[1][t]), fmaxf(shi[2][t], shi[3][t]));
      if (hi - lo < 1e-8f) { lo = lo - 0.5f; hi = hi + 0.5f; }
      float d = hi - lo;
      float* fp = featp + t * 12;
      fp[0] = lo;
      fp[1] = 8.0f / d;   // u = (x-lo)*ih maps grid to integers 0..8
      #pragma unroll
      for (int c = 0; c < 4; ++c) {
        float a = softplus_f(wscale[t * 4 + c]) + 1e-6f;
        fp[2 + c] = 1.0f / a;
        fp[6 + c] = wshift[t * 4 + c];
      }
      fp[10] = 0.f; fp[11] = 0.f;
    }
    if (t >= 128 && t < 160) {
      int o = t - 128;
      ebias[o] = softplus_f(alpha[0]) * bias[o];
    }
  }
}

// ---------------- pass 3: main fused kernel (zero-LDS main loop) ----------------
// 256 threads = 4 waves, one 16-sample tile, K-split 4 ways. Wave w owns features
// [w*16, w*16+16). Lane (col,kg) computes feature w*16+kg*4+c for sample col in
// pass c; the k-permutation makes its 48 values exactly its own A-fragments.
// NOTE: no min-wave launch bound — forcing 4 waves/EU (VGPR<=128) caused spills (R5).
__global__ __launch_bounds__(256) void k_main(const float* __restrict__ X,
                                              const unsigned short* __restrict__ Csw,
                                              const float* __restrict__ featp,
                                              const float* __restrict__ ebias,
                                              float* __restrict__ out) {
  __shared__ float red[3][512];

  int t = threadIdx.x;
  int w = t >> 6, lane = t & 63;
  int col = lane & 15, kg = lane >> 4;
  int sbase = blockIdx.x * 16;

  // one float4 load: x for this lane's 4 passes (features w*16 + kg*4 + {0..3})
  const float4* X4 = (const float4*)X;
  float4 xq = X4[(sbase + col) * 16 + w * 4 + kg];
  float xr[4] = {xq.x, xq.y, xq.z, xq.w};

  f32x4 acc0 = {0.f, 0.f, 0.f, 0.f};
  f32x4 acc1 = {0.f, 0.f, 0.f, 0.f};
  const bf16x8* CB = reinterpret_cast<const bf16x8*>(Csw);
  const bf16x8* CBw = CB + (size_t)w * 3072 + kg * 32;

  bf16x8 B0, B1, B2, B3, B4, B5, B6, B7, B8, B9, B10, B11;
#define LOADB(cc) do { const bf16x8* p_ = CBw + (size_t)(cc) * 768;            \
    B0 = p_[col];        B1 = p_[col + 16];                                    \
    B2 = p_[128 + col];  B3 = p_[128 + col + 16];                              \
    B4 = p_[256 + col];  B5 = p_[256 + col + 16];                              \
    B6 = p_[384 + col];  B7 = p_[384 + col + 16];                              \
    B8 = p_[512 + col];  B9 = p_[512 + col + 16];                              \
    B10 = p_[640 + col]; B11 = p_[640 + col + 16]; } while (0)

  LOADB(0);

  #pragma unroll 1
  for (int c = 0; c < 4; ++c) {
    int f = w * 16 + kg * 4 + c;
    const float4* fq = (const float4*)(featp + f * 12);
    float4 q0 = fq[0];   // xmin, ih, inva0, inva1
    float4 q1 = fq[1];   // inva2, inva3, shift0, shift1
    float4 q2 = fq[2];   // shift2, shift3, -, -
    float x = xr[c];

    bf16x8 A0, A1, A2, A3, A4, A5;
    A0[0] = (__bf16)x;                       // k0: identity

    // ---- B-spline, normalized coords: u in [0,8], integer knots ----
    {
      float u = (x - q0.x) * q0.y;
      int ji = (int)u;
      float e0 = (ji == 0) ? 1.f : 0.f;
      float e1 = (ji == 1) ? 1.f : 0.f;
      float e2 = (ji == 2) ? 1.f : 0.f;
      float e3 = (ji == 3) ? 1.f : 0.f;
      float e4 = (ji == 4) ? 1.f : 0.f;
      float e5 = (ji == 5) ? 1.f : 0.f;
      float e6 = (ji == 6) ? 1.f : 0.f;
      float e7 = (ji == 7) ? 1.f : 0.f;
      float d0 = u,       d1 = u - 1.f, d2 = u - 2.f, d3 = u - 3.f, d4 = u - 4.f;
      float d5 = u - 5.f, d6 = u - 6.f, d7 = u - 7.f, d8 = u - 8.f;
      float a2 = -d1 * e0;
      float a3 = d0 * e0 - d2 * e1;
      float a4 = d1 * e1 - d3 * e2;
      float a5 = d2 * e2 - d4 * e3;
      float a6 = d3 * e3 - d5 * e4;
      float a7 = d4 * e4 - d6 * e5;
      float a8 = d5 * e5 - d7 * e6;
      float a9 = d6 * e6 - d8 * e7;
      float a10 = d7 * e7;
      float h0 = 0.5f * d0, h2 = 0.5f * d2, h3 = 0.5f * d3, h4 = 0.5f * d4;
      float h1 = 0.5f * d1, h5 = 0.5f * d5, h6 = 0.5f * d6, h7 = 0.5f * d7, h8 = 0.5f * d8;
      float c1v = -d1 * a2;
      float c2v = d0 * a2 - h2 * a3;
      float c3v = h0 * a3 - h3 * a4;
      float c4v = h1 * a4 - h4 * a5;
      float c5v = h2 * a5 - h5 * a6;
      float c6v = h3 * a6 - h6 * a7;
      float c7v = h4 * a7 - h7 * a8;
      float c8v = h5 * a8 - h8 * a9;
      float c9v = h6 * a9 - d8 * a10;
      float c10v = d7 * a10;
      const float TH = 0.33333333333333f;
      A0[1] = (__bf16)(-d1 * c1v);
      A0[2] = (__bf16)(d0 * c1v - h2 * c2v);
      A0[3] = (__bf16)(h0 * c2v - TH * (d3 * c3v));
      A0[4] = (__bf16)((d0 * c3v - d4 * c4v) * TH);
      A0[5] = (__bf16)((d1 * c4v - d5 * c5v) * TH);
      A0[6] = (__bf16)((d2 * c5v - d6 * c6v) * TH);
      A0[7] = (__bf16)((d3 * c6v - d7 * c7v) * TH);
      A1[0] = (__bf16)((d4 * c7v - d8 * c8v) * TH);
      A1[1] = (__bf16)(TH * (d5 * c8v) - h8 * c9v);
      A1[2] = (__bf16)(h6 * c9v - d8 * c10v);
      A1[3] = (__bf16)(d7 * c10v);
    }
    // ---- Taylor (k12-15) ----
    {
      float x2 = x * x;
      A1[4] = (__bf16)1.0f;
      A1[5] = (__bf16)x;
      A1[6] = (__bf16)(x2 * 0.5f);
      A1[7] = (__bf16)(x2 * x * (1.0f / 6.0f));
    }
    // ---- Jacobi (k16-20) ----
    {
      float j1 = 1.41421356237f * x;
      float j2 = (1.5f * x * j1 - 0.6f) * 0.57735026919f;
      float j3 = (1.6f * x * j2 - 0.685714285714f * j1) * 0.5f;
      float j4 = (1.66666666667f * x * j3 - 0.740740740741f * j2) * 0.44721359550f;
      A2[0] = (__bf16)1.0f;
      A2[1] = (__bf16)j1;
      A2[2] = (__bf16)j2;
      A2[3] = (__bf16)j3;
      A2[4] = (__bf16)j4;
    }
    // ---- Chebyshev (k21-25) ----
    {
      float xc = fminf(fmaxf(x, -1e6f), 1e6f);
      float cc2 = 2.0f * xc * xc - 1.0f;
      float cc3 = 2.0f * xc * cc2 - xc;
      float cc4 = 2.0f * xc * cc3 - cc2;
      A2[5] = (__bf16)1.0f;
      A2[6] = (__bf16)(xc * 0.70710678119f);
      A2[7] = (__bf16)(cc2 * 0.57735026919f);
      A3[0] = (__bf16)(cc3 * 0.5f);
      A3[1] = (__bf16)(cc4 * 0.44721359550f);
    }
    // ---- Fourier (k26-41): angle-doubling tree (dep depth ~3 vs 7) ----
    {
      float s1 = __sinf(x), c1f = __cosf(x);
      float c2f = 2.0f * c1f * c1f - 1.0f, s2f = 2.0f * s1 * c1f;
      float c3f = c2f * c1f - s2f * s1,    s3f = s2f * c1f + c2f * s1;
      float c4f = 2.0f * c2f * c2f - 1.0f, s4f = 2.0f * s2f * c2f;
      float c5f = c4f * c1f - s4f * s1,    s5f = s4f * c1f + c4f * s1;
      float c6f = c4f * c2f - s4f * s2f,   s6f = s4f * c2f + c4f * s2f;
      float c7f = c4f * c3f - s4f * s3f,   s7f = s4f * c3f + c4f * s3f;
      float c8f = 2.0f * c4f * c4f - 1.0f, s8f = 2.0f * s4f * c4f;
      A3[2] = (__bf16)(c1f * 0.25f);
      A3[3] = (__bf16)(c2f * 0.25f);
      A3[4] = (__bf16)(c3f * 0.25f);
      A3[5] = (__bf16)(c4f * 0.25f);
      A3[6] = (__bf16)(c5f * 0.25f);
      A3[7] = (__bf16)(c6f * 0.25f);
      A4[0] = (__bf16)(c7f * 0.25f);
      A4[1] = (__bf16)(c8f * 0.25f);
      A4[2] = (__bf16)(s1 * 0.25f);
      A4[3] = (__bf16)(s2f * 0.25f);
      A4[4] = (__bf16)(s3f * 0.25f);
      A4[5] = (__bf16)(s4f * 0.25f);
      A4[6] = (__bf16)(s5f * 0.25f);
      A4[7] = (__bf16)(s6f * 0.25f);
      A5[0] = (__bf16)(s7f * 0.25f);
      A5[1] = (__bf16)(s8f * 0.25f);
    }
    // ---- Wavelet (k42-45) + pad (k46-47) ----
    {
      float u0 = (x - q1.z) * q0.z, u1 = (x - q1.w) * q0.w;
      float u2 = (x - q2.x) * q1.x, u3 = (x - q2.y) * q1.y;
      float s0 = u0 * u0, s1w = u1 * u1, s2w = u2 * u2, s3 = u3 * u3;
      A5[2] = (__bf16)((s0 - 1.0f) * __expf(-0.5f * s0));
      A5[3] = (__bf16)((s1w - 1.0f) * __expf(-0.5f * s1w));
      A5[4] = (__bf16)((s2w - 1.0f) * __expf(-0.5f * s2w));
      A5[5] = (__bf16)((s3 - 1.0f) * __expf(-0.5f * s3));
      A5[6] = (__bf16)0.0f;
      A5[7] = (__bf16)0.0f;
    }

    // ---- MFMA: 6 K-steps, A and B both from registers; no LDS, no barriers ----
    acc0 = __builtin_amdgcn_mfma_f32_16x16x32_bf16(A0, B0, acc0, 0, 0, 0);
    acc1 = __builtin_amdgcn_mfma_f32_16x16x32_bf16(A0, B1, acc1, 0, 0, 0);
    acc0 = __builtin_amdgcn_mfma_f32_16x16x32_bf16(A1, B2, acc0, 0, 0, 0);
    acc1 = __builtin_amdgcn_mfma_f32_16x16x32_bf16(A1, B3, acc1, 0, 0, 0);
    acc0 = __builtin_amdgcn_mfma_f32_16x16x32_bf16(A2, B4, acc0, 0, 0, 0);
    acc1 = __builtin_amdgcn_mfma_f32_16x16x32_bf16(A2, B5, acc1, 0, 0, 0);
    acc0 = __builtin_amdgcn_mfma_f32_16x16x32_bf16(A3, B6, acc0, 0, 0, 0);
    acc1 = __builtin_amdgcn_mfma_f32_16x16x32_bf16(A3, B7, acc1, 0, 0, 0);
    acc0 = __builtin_amdgcn_mfma_f32_16x16x32_bf16(A4, B8, acc0, 0, 0, 0);
    acc1 = __builtin_amdgcn_mfma_f32_16x16x32_bf16(A4, B9, acc1, 0, 0, 0);
    acc0 = __builtin_amdgcn_mfma_f32_16x16x32_bf16(A5, B10, acc0, 0, 0, 0);
    acc1 = __builtin_amdgcn_mfma_f32_16x16x32_bf16(A5, B11, acc1, 0, 0, 0);

    if (c < 3) LOADB(c + 1);
  }
#undef LOADB

  // ---- 4-way cross-wave K-reduction (single barrier) ----
  if (w > 0) {
    float* rw = &red[w - 1][0];
    #pragma unroll
    for (int j = 0; j < 4; ++j) {
      rw[(kg * 4 + j) * 32 + col]      = acc0[j];
      rw[(kg * 4 + j) * 32 + col + 16] = acc1[j];
    }
  }
  __syncthreads();
  if (w == 0) {
    float eb0 = ebias[col], eb1 = ebias[col + 16];
    #pragma unroll
    for (int j = 0; j < 4; ++j) {
      int idx0 = (kg * 4 + j) * 32 + col;
      int idx1 = idx0 + 16;
      int row = sbase + kg * 4 + j;
      out[row * 32 + col]      = acc0[j] + red[0][idx0] + red[1][idx0] + red[2][idx0] + eb0;
      out[row * 32 + col + 16] = acc1[j] + red[0][idx1] + red[1][idx1] + red[2][idx1] + eb1;
    }
  }
}

extern "C" void kernel_launch(void* const* d_in, const int* in_sizes, int n_in,
                              void* d_out, int out_size, void* d_ws, size_t ws_size,
                              hipStream_t stream) {
  const float* X   = (const float*)d_in[0];
  const float* bv  = (const float*)d_in[1];
  const float* bg  = (const float*)d_in[2];
  const float* bbi = (const float*)d_in[3];
  const float* bsp = (const float*)d_in[4];
  const float* tay = (const float*)d_in[5];
  const float* jac = (const float*)d_in[6];
  const float* che = (const float*)d_in[7];
  const float* fou = (const float*)d_in[8];
  const float* wav = (const float*)d_in[9];
  const float* wsc = (const float*)d_in[10];
  const float* wsh = (const float*)d_in[11];
  const float* gns = (const float*)d_in[12];
  const float* alp = (const float*)d_in[13];
  const float* bet = (const float*)d_in[14];
  const float* mxl = (const float*)d_in[15];
  float* out = (float*)d_out;

  uint8_t* w = (uint8_t*)d_ws;
  float* pmin  = (float*)(w + OFF_PMIN);
  float* pmax  = (float*)(w + OFF_PMAX);
  float* featp = (float*)(w + OFF_FEAT);
  float* ebias = (float*)(w + OFF_EB);
  unsigned short* Csw = (unsigned short*)(w + OFF_CSW);

  k_minmax<<<64, 256, 0, stream>>>(X, pmin, pmax);
  k_setup<<<9, 256, 0, stream>>>(pmin, pmax, wsc, wsh, alp, bbi,
                                 bv, bg, bsp, tay, jac, che, fou, wav,
                                 gns, bet, mxl, featp, ebias, Csw);
  k_main<<<2048, 256, 0, stream>>>(X, Csw, featp, ebias, out);
}

// Round 7
// 32.574 us; speedup vs baseline: 1.5831x; 1.1964x over previous
//
#include <hip/hip_runtime.h>
#include <stdint.h>

#define NB   32768
#define NIN  64
#define NOUT 32
// ws layout (bytes)
#define OFF_PMIN 0          // 64*64*4 = 16384
#define OFF_PMAX 16384      // 16384
#define OFF_FEAT 32768      // 64*12*4 = 3072
#define OFF_EB   35840      // 32*4 = 128
#define OFF_CSW  35968      // 2560*32*2 = 163840 (16B aligned)

typedef __bf16 bf16x8 __attribute__((ext_vector_type(8)));
typedef float  f32x4  __attribute__((ext_vector_type(4)));

__device__ __forceinline__ float softplus_f(float x) {
  return fmaxf(x, 0.0f) + log1pf(expf(-fabsf(x)));
}

// ---------------- pass 1: per-feature min/max partials (float4, 64 blocks) ----------------
__global__ __launch_bounds__(256) void k_minmax(const float* __restrict__ X,
                                                float* __restrict__ pmin,
                                                float* __restrict__ pmax) {
  const float4* X4 = (const float4*)X;
  int t = threadIdx.x;
  int g = t & 15, r = t >> 4;
  float4 lo = {3.402823466e38f, 3.402823466e38f, 3.402823466e38f, 3.402823466e38f};
  float4 hi = {-3.402823466e38f, -3.402823466e38f, -3.402823466e38f, -3.402823466e38f};
  int base = blockIdx.x * 8192;  // 512 rows * 16 f4
  #pragma unroll 8
  for (int k = 0; k < 32; ++k) {
    float4 v = X4[base + k * 256 + t];
    lo.x = fminf(lo.x, v.x); lo.y = fminf(lo.y, v.y);
    lo.z = fminf(lo.z, v.z); lo.w = fminf(lo.w, v.w);
    hi.x = fmaxf(hi.x, v.x); hi.y = fmaxf(hi.y, v.y);
    hi.z = fmaxf(hi.z, v.z); hi.w = fmaxf(hi.w, v.w);
  }
  __shared__ float4 slo[16][16], shi[16][16];
  slo[r][g] = lo; shi[r][g] = hi;
  __syncthreads();
  if (t < 64) {
    int gg = t >> 2, c = t & 3;
    float l = 3.402823466e38f, h = -3.402823466e38f;
    #pragma unroll
    for (int rr = 0; rr < 16; ++rr) {
      const float* pl = (const float*)&slo[rr][gg];
      const float* ph = (const float*)&shi[rr][gg];
      l = fminf(l, pl[c]); h = fmaxf(h, ph[c]);
    }
    pmin[blockIdx.x * 64 + t] = l;
    pmax[blockIdx.x * 64 + t] = h;
  }
}

// ---------------- pass 2: fused setup: blocks 0-7 = coef, block 8 = feat params ----------------
// 40-slot basis per feature (5 bf16x8 groups):
//  g0: bsp0..7 | g1: bsp8..10, x, x^2, x^3, x^4, 1 | g2: cos1..8 | g3: sin1..8 | g4: wav0..3,0,0,0,0
// Taylor/Jacobi/Cheby folded into monomial coefs; Fourier 1/4 and identity W folded too.
// frag unit (bf16x8): ((wv*20 + cc*5 + s)*4 + kgi)*32 + o   for feature i = wv*16+kgi*4+cc.
__global__ __launch_bounds__(256) void k_setup(const float* __restrict__ pmin,
                                               const float* __restrict__ pmax,
                                               const float* __restrict__ wscale,
                                               const float* __restrict__ wshift,
                                               const float* __restrict__ alpha,
                                               const float* __restrict__ bias,
                                               const float* __restrict__ base_v,
                                               const float* __restrict__ base_g,
                                               const float* __restrict__ bsp,
                                               const float* __restrict__ tay,
                                               const float* __restrict__ jac,
                                               const float* __restrict__ che,
                                               const float* __restrict__ fou,
                                               const float* __restrict__ wav,
                                               const float* __restrict__ gains,
                                               const float* __restrict__ beta,
                                               const float* __restrict__ mixl,
                                               float* __restrict__ featp,
                                               float* __restrict__ ebias,
                                               unsigned short* __restrict__ Csw) {
  int t = threadIdx.x;
  if (blockIdx.x < 8) {
    int o = blockIdx.x * 4 + (t >> 6);
    int i = t & 63;
    int p = o * 64 + i;
    float spa = softplus_f(alpha[0]);
    float spb = softplus_f(beta[0]);
    float spg[6];
    #pragma unroll
    for (int f = 0; f < 6; ++f) spg[f] = softplus_f(gains[f]);
    float m[6], mmax = -3.402823466e38f;
    #pragma unroll
    for (int f = 0; f < 6; ++f) { m[f] = mixl[p * 6 + f] * 0.5f; mmax = fmaxf(mmax, m[f]); }
    float es = 0.f;
    #pragma unroll
    for (int f = 0; f < 6; ++f) { m[f] = __expf(m[f] - mmax); es += m[f]; }
    float inv = 1.0f / es;

    float vv = base_v[p];
    float s2 = vv * vv;
    #pragma unroll
    for (int d = 1; d < 64; d <<= 1) s2 += __shfl_xor(s2, d);
    float vn = sqrtf(s2);
    float Wid = spa * base_g[o] * vv / vn;   // identity path: sp(alpha)*W[o,i]

    float wB = spb * spg[0] * m[0] * inv;
    float wT = spb * spg[1] * m[1] * inv;
    float wJ = spb * spg[2] * m[2] * inv;
    float wC = spb * spg[3] * m[3] * inv;
    float wF = spb * spg[4] * m[4] * inv * 0.25f;
    float wW = spb * spg[5] * m[5] * inv;

    float j0 = jac[p * 5 + 0], j1 = jac[p * 5 + 1], j2 = jac[p * 5 + 2],
          j3 = jac[p * 5 + 3], j4 = jac[p * 5 + 4];
    float c0 = che[p * 5 + 0], c1 = che[p * 5 + 1], c2 = che[p * 5 + 2],
          c3 = che[p * 5 + 3], c4 = che[p * 5 + 4];
    float t0 = tay[p * 4 + 0], t1 = tay[p * 4 + 1], t2 = tay[p * 4 + 2], t3 = tay[p * 4 + 3];

    float slot[40];
    #pragma unroll
    for (int k = 0; k < 11; ++k) slot[k] = wB * bsp[p * 11 + k];
    // monomial folds (verified vs reference recurrences at x=1)
    slot[11] = Wid + wT * t1
             + wJ * (1.4142136f * j1 - 0.7619780f * j3)
             + wC * (0.7071068f * c1 - 1.5f * c3);                       // x
    slot[12] = wT * 0.5f * t2
             + wJ * (1.2247449f * j2 - 0.9736894f * j4)
             + wC * (1.1547005f * c2 - 3.5777088f * c4);                 // x^2
    slot[13] = wT * (1.0f / 6.0f) * t3
             + wJ * 0.9797959f * j3
             + wC * 2.0f * c3;                                           // x^3
    slot[14] = wJ * 0.7302967f * j4 + wC * 3.5777088f * c4;              // x^4
    slot[15] = wT * t0
             + wJ * (j0 - 0.3464102f * j2 + 0.1147551f * j4)
             + wC * (c0 - 0.5773503f * c2 + 0.4472136f * c4);            // 1
    #pragma unroll
    for (int k = 0; k < 8; ++k) slot[16 + k] = wF * fou[p * 16 + k];      // cos
    #pragma unroll
    for (int k = 0; k < 8; ++k) slot[24 + k] = wF * fou[p * 16 + 8 + k];  // sin
    #pragma unroll
    for (int k = 0; k < 4; ++k) slot[32 + k] = wW * wav[p * 4 + k];
    slot[36] = 0.f; slot[37] = 0.f; slot[38] = 0.f; slot[39] = 0.f;

    int wv = i >> 4, kgi = (i >> 2) & 3, cc = i & 3;
    bf16x8* CBo = reinterpret_cast<bf16x8*>(Csw);
    #pragma unroll
    for (int s = 0; s < 5; ++s) {
      bf16x8 pk;
      #pragma unroll
      for (int j = 0; j < 8; ++j) pk[j] = (__bf16)slot[s * 8 + j];
      int st = wv * 20 + cc * 5 + s;
      CBo[(st * 4 + kgi) * 32 + o] = pk;
    }
  } else {
    __shared__ float slo[4][64], shi[4][64];
    int i = t & 63, cg = t >> 6;
    float lo = 3.402823466e38f, hi = -3.402823466e38f;
    #pragma unroll
    for (int pp = 0; pp < 16; ++pp) {
      int p = pp * 4 + cg;
      lo = fminf(lo, pmin[p * 64 + i]);
      hi = fmaxf(hi, pmax[p * 64 + i]);
    }
    slo[cg][i] = lo; shi[cg][i] = hi;
    __syncthreads();
    if (t < 64) {
      lo = fminf(fminf(slo[0][t], slo[1][t]), fminf(slo[2][t], slo[3][t]));
      hi = fmaxf(fmaxf(shi[0][t], shi[1][t]), fmaxf(shi[2][t], shi[3][t]));
      if (hi - lo < 1e-8f) { lo = lo - 0.5f; hi = hi + 0.5f; }
      float d = hi - lo;
      float* fp = featp + t * 12;
      fp[0] = lo;
      fp[1] = 8.0f / d;   // u = (x-lo)*ih maps grid to integers 0..8
      #pragma unroll
      for (int c = 0; c < 4; ++c) {
        float a = softplus_f(wscale[t * 4 + c]) + 1e-6f;
        fp[2 + c] = 1.0f / a;
        fp[6 + c] = wshift[t * 4 + c];
      }
      fp[10] = 0.f; fp[11] = 0.f;
    }
    if (t >= 128 && t < 160) {
      int o = t - 128;
      ebias[o] = softplus_f(alpha[0]) * bias[o];
    }
  }
}

// ---------------- 40-slot basis -> 5 A-fragments (all in registers) ----------------
__device__ __forceinline__ void basis40(float x, float4 q0, float4 q1, float4 q2,
                                        bf16x8& A0, bf16x8& A1, bf16x8& A2,
                                        bf16x8& A3, bf16x8& A4) {
  // ---- B-spline, normalized coords: u in [0,8], integer knots ----
  {
    float u = (x - q0.x) * q0.y;
    int ji = (int)u;
    float e0 = (ji == 0) ? 1.f : 0.f;
    float e1 = (ji == 1) ? 1.f : 0.f;
    float e2 = (ji == 2) ? 1.f : 0.f;
    float e3 = (ji == 3) ? 1.f : 0.f;
    float e4 = (ji == 4) ? 1.f : 0.f;
    float e5 = (ji == 5) ? 1.f : 0.f;
    float e6 = (ji == 6) ? 1.f : 0.f;
    float e7 = (ji == 7) ? 1.f : 0.f;
    float d0 = u,       d1 = u - 1.f, d2 = u - 2.f, d3 = u - 3.f, d4 = u - 4.f;
    float d5 = u - 5.f, d6 = u - 6.f, d7 = u - 7.f, d8 = u - 8.f;
    float a2 = -d1 * e0;
    float a3 = d0 * e0 - d2 * e1;
    float a4 = d1 * e1 - d3 * e2;
    float a5 = d2 * e2 - d4 * e3;
    float a6 = d3 * e3 - d5 * e4;
    float a7 = d4 * e4 - d6 * e5;
    float a8 = d5 * e5 - d7 * e6;
    float a9 = d6 * e6 - d8 * e7;
    float a10 = d7 * e7;
    float h0 = 0.5f * d0, h1 = 0.5f * d1, h2 = 0.5f * d2, h3 = 0.5f * d3, h4 = 0.5f * d4;
    float h5 = 0.5f * d5, h6 = 0.5f * d6, h7 = 0.5f * d7, h8 = 0.5f * d8;
    float c1v = -d1 * a2;
    float c2v = d0 * a2 - h2 * a3;
    float c3v = h0 * a3 - h3 * a4;
    float c4v = h1 * a4 - h4 * a5;
    float c5v = h2 * a5 - h5 * a6;
    float c6v = h3 * a6 - h6 * a7;
    float c7v = h4 * a7 - h7 * a8;
    float c8v = h5 * a8 - h8 * a9;
    float c9v = h6 * a9 - d8 * a10;
    float c10v = d7 * a10;
    const float TH = 0.33333333333333f;
    A0[0] = (__bf16)(-d1 * c1v);
    A0[1] = (__bf16)(d0 * c1v - h2 * c2v);
    A0[2] = (__bf16)(h0 * c2v - TH * (d3 * c3v));
    A0[3] = (__bf16)((d0 * c3v - d4 * c4v) * TH);
    A0[4] = (__bf16)((d1 * c4v - d5 * c5v) * TH);
    A0[5] = (__bf16)((d2 * c5v - d6 * c6v) * TH);
    A0[6] = (__bf16)((d3 * c6v - d7 * c7v) * TH);
    A0[7] = (__bf16)((d4 * c7v - d8 * c8v) * TH);
    A1[0] = (__bf16)(TH * (d5 * c8v) - h8 * c9v);
    A1[1] = (__bf16)(h6 * c9v - d8 * c10v);
    A1[2] = (__bf16)(d7 * c10v);
  }
  // ---- monomials x, x^2, x^3, x^4, 1 ----
  {
    float x2 = x * x, x3v = x2 * x, x4v = x2 * x2;
    A1[3] = (__bf16)x;
    A1[4] = (__bf16)x2;
    A1[5] = (__bf16)x3v;
    A1[6] = (__bf16)x4v;
    A1[7] = (__bf16)1.0f;
  }
  // ---- Fourier cos1..8 / sin1..8 (unscaled; angle-doubling tree) ----
  {
    float s1 = __sinf(x), c1f = __cosf(x);
    float c2f = 2.0f * c1f * c1f - 1.0f, s2f = 2.0f * s1 * c1f;
    float c3f = c2f * c1f - s2f * s1,    s3f = s2f * c1f + c2f * s1;
    float c4f = 2.0f * c2f * c2f - 1.0f, s4f = 2.0f * s2f * c2f;
    float c5f = c4f * c1f - s4f * s1,    s5f = s4f * c1f + c4f * s1;
    float c6f = c4f * c2f - s4f * s2f,   s6f = s4f * c2f + c4f * s2f;
    float c7f = c4f * c3f - s4f * s3f,   s7f = s4f * c3f + c4f * s3f;
    float c8f = 2.0f * c4f * c4f - 1.0f, s8f = 2.0f * s4f * c4f;
    A2[0] = (__bf16)c1f; A2[1] = (__bf16)c2f; A2[2] = (__bf16)c3f; A2[3] = (__bf16)c4f;
    A2[4] = (__bf16)c5f; A2[5] = (__bf16)c6f; A2[6] = (__bf16)c7f; A2[7] = (__bf16)c8f;
    A3[0] = (__bf16)s1;  A3[1] = (__bf16)s2f; A3[2] = (__bf16)s3f; A3[3] = (__bf16)s4f;
    A3[4] = (__bf16)s5f; A3[5] = (__bf16)s6f; A3[6] = (__bf16)s7f; A3[7] = (__bf16)s8f;
  }
  // ---- Wavelet ----
  {
    float u0 = (x - q1.z) * q0.z, u1 = (x - q1.w) * q0.w;
    float u2 = (x - q2.x) * q1.x, u3 = (x - q2.y) * q1.y;
    float s0 = u0 * u0, s1w = u1 * u1, s2w = u2 * u2, s3 = u3 * u3;
    A4[0] = (__bf16)((s0 - 1.0f) * __expf(-0.5f * s0));
    A4[1] = (__bf16)((s1w - 1.0f) * __expf(-0.5f * s1w));
    A4[2] = (__bf16)((s2w - 1.0f) * __expf(-0.5f * s2w));
    A4[3] = (__bf16)((s3 - 1.0f) * __expf(-0.5f * s3));
    A4[4] = (__bf16)0.0f; A4[5] = (__bf16)0.0f;
    A4[6] = (__bf16)0.0f; A4[7] = (__bf16)0.0f;
  }
}

// ---------------- pass 3: main fused kernel (zero-LDS loop, dual sample tile) ----------------
// 256 threads = 4 waves, TWO 16-sample tiles (32 samples/block), K-split 4 ways.
// Wave w: features [w*16,w*16+16). Lane (col,kg): pass c computes feature w*16+kg*4+c
// for sample col (tile0) and col+16 (tile1); both tiles share the same B fragments.
__global__ __launch_bounds__(256) void k_main(const float* __restrict__ X,
                                              const unsigned short* __restrict__ Csw,
                                              const float* __restrict__ featp,
                                              const float* __restrict__ ebias,
                                              float* __restrict__ out) {
  __shared__ float red[3][1024];

  int t = threadIdx.x;
  int w = t >> 6, lane = t & 63;
  int col = lane & 15, kg = lane >> 4;
  int sbase = blockIdx.x * 32;

  const float4* X4 = (const float4*)X;
  float4 xq0 = X4[(sbase + col) * 16 + w * 4 + kg];
  float4 xq1 = X4[(sbase + 16 + col) * 16 + w * 4 + kg];
  float xr0[4] = {xq0.x, xq0.y, xq0.z, xq0.w};
  float xr1[4] = {xq1.x, xq1.y, xq1.z, xq1.w};

  f32x4 acc00 = {0.f, 0.f, 0.f, 0.f};
  f32x4 acc01 = {0.f, 0.f, 0.f, 0.f};
  f32x4 acc10 = {0.f, 0.f, 0.f, 0.f};
  f32x4 acc11 = {0.f, 0.f, 0.f, 0.f};
  const bf16x8* CB = reinterpret_cast<const bf16x8*>(Csw);
  const bf16x8* CBw = CB + (size_t)w * 2560 + kg * 32;

  bf16x8 B0, B1, B2, B3, B4, B5, B6, B7, B8, B9;
#define LOADB(cc) do { const bf16x8* p_ = CBw + (size_t)(cc) * 640;            \
    B0 = p_[col];        B1 = p_[col + 16];                                    \
    B2 = p_[128 + col];  B3 = p_[128 + col + 16];                              \
    B4 = p_[256 + col];  B5 = p_[256 + col + 16];                              \
    B6 = p_[384 + col];  B7 = p_[384 + col + 16];                              \
    B8 = p_[512 + col];  B9 = p_[512 + col + 16]; } while (0)

  LOADB(0);

  #pragma unroll 1
  for (int c = 0; c < 4; ++c) {
    int f = w * 16 + kg * 4 + c;
    const float4* fq = (const float4*)(featp + f * 12);
    float4 q0 = fq[0];   // xmin, ih, inva0, inva1
    float4 q1 = fq[1];   // inva2, inva3, shift0, shift1
    float4 q2 = fq[2];   // shift2, shift3, -, -

    bf16x8 A0, A1, A2, A3, A4;

    // tile 0
    basis40(xr0[c], q0, q1, q2, A0, A1, A2, A3, A4);
    acc00 = __builtin_amdgcn_mfma_f32_16x16x32_bf16(A0, B0, acc00, 0, 0, 0);
    acc01 = __builtin_amdgcn_mfma_f32_16x16x32_bf16(A0, B1, acc01, 0, 0, 0);
    acc00 = __builtin_amdgcn_mfma_f32_16x16x32_bf16(A1, B2, acc00, 0, 0, 0);
    acc01 = __builtin_amdgcn_mfma_f32_16x16x32_bf16(A1, B3, acc01, 0, 0, 0);
    acc00 = __builtin_amdgcn_mfma_f32_16x16x32_bf16(A2, B4, acc00, 0, 0, 0);
    acc01 = __builtin_amdgcn_mfma_f32_16x16x32_bf16(A2, B5, acc01, 0, 0, 0);
    acc00 = __builtin_amdgcn_mfma_f32_16x16x32_bf16(A3, B6, acc00, 0, 0, 0);
    acc01 = __builtin_amdgcn_mfma_f32_16x16x32_bf16(A3, B7, acc01, 0, 0, 0);
    acc00 = __builtin_amdgcn_mfma_f32_16x16x32_bf16(A4, B8, acc00, 0, 0, 0);
    acc01 = __builtin_amdgcn_mfma_f32_16x16x32_bf16(A4, B9, acc01, 0, 0, 0);

    // tile 1 (same B fragments)
    basis40(xr1[c], q0, q1, q2, A0, A1, A2, A3, A4);
    acc10 = __builtin_amdgcn_mfma_f32_16x16x32_bf16(A0, B0, acc10, 0, 0, 0);
    acc11 = __builtin_amdgcn_mfma_f32_16x16x32_bf16(A0, B1, acc11, 0, 0, 0);
    acc10 = __builtin_amdgcn_mfma_f32_16x16x32_bf16(A1, B2, acc10, 0, 0, 0);
    acc11 = __builtin_amdgcn_mfma_f32_16x16x32_bf16(A1, B3, acc11, 0, 0, 0);
    acc10 = __builtin_amdgcn_mfma_f32_16x16x32_bf16(A2, B4, acc10, 0, 0, 0);
    acc11 = __builtin_amdgcn_mfma_f32_16x16x32_bf16(A2, B5, acc11, 0, 0, 0);
    acc10 = __builtin_amdgcn_mfma_f32_16x16x32_bf16(A3, B6, acc10, 0, 0, 0);
    acc11 = __builtin_amdgcn_mfma_f32_16x16x32_bf16(A3, B7, acc11, 0, 0, 0);
    acc10 = __builtin_amdgcn_mfma_f32_16x16x32_bf16(A4, B8, acc10, 0, 0, 0);
    acc11 = __builtin_amdgcn_mfma_f32_16x16x32_bf16(A4, B9, acc11, 0, 0, 0);

    if (c < 3) LOADB(c + 1);   // after tile1 consumed B; hides under next tile0 basis
  }
#undef LOADB

  // ---- 4-way cross-wave K-reduction (single barrier) ----
  if (w > 0) {
    float* rw = &red[w - 1][0];
    #pragma unroll
    for (int j = 0; j < 4; ++j) {
      int idx = (kg * 4 + j) * 32 + col;
      rw[idx]            = acc00[j];
      rw[idx + 16]       = acc01[j];
      rw[512 + idx]      = acc10[j];
      rw[512 + idx + 16] = acc11[j];
    }
  }
  __syncthreads();
  if (w == 0) {
    float eb0 = ebias[col], eb1 = ebias[col + 16];
    #pragma unroll
    for (int j = 0; j < 4; ++j) {
      int idx0 = (kg * 4 + j) * 32 + col;
      int idx1 = idx0 + 16;
      int row0 = sbase + kg * 4 + j;
      int row1 = row0 + 16;
      out[row0 * 32 + col]      = acc00[j] + red[0][idx0] + red[1][idx0] + red[2][idx0] + eb0;
      out[row0 * 32 + col + 16] = acc01[j] + red[0][idx1] + red[1][idx1] + red[2][idx1] + eb1;
      out[row1 * 32 + col]      = acc10[j] + red[0][512 + idx0] + red[1][512 + idx0] + red[2][512 + idx0] + eb0;
      out[row1 * 32 + col + 16] = acc11[j] + red[0][512 + idx1] + red[1][512 + idx1] + red[2][512 + idx1] + eb1;
    }
  }
}

extern "C" void kernel_launch(void* const* d_in, const int* in_sizes, int n_in,
                              void* d_out, int out_size, void* d_ws, size_t ws_size,
                              hipStream_t stream) {
  const float* X   = (const float*)d_in[0];
  const float* bv  = (const float*)d_in[1];
  const float* bg  = (const float*)d_in[2];
  const float* bbi = (const float*)d_in[3];
  const float* bsp = (const float*)d_in[4];
  const float* tay = (const float*)d_in[5];
  const float* jac = (const float*)d_in[6];
  const float* che = (const float*)d_in[7];
  const float* fou = (const float*)d_in[8];
  const float* wav = (const float*)d_in[9];
  const float* wsc = (const float*)d_in[10];
  const float* wsh = (const float*)d_in[11];
  const float* gns = (const float*)d_in[12];
  const float* alp = (const float*)d_in[13];
  const float* bet = (const float*)d_in[14];
  const float* mxl = (const float*)d_in[15];
  float* out = (float*)d_out;

  uint8_t* w = (uint8_t*)d_ws;
  float* pmin  = (float*)(w + OFF_PMIN);
  float* pmax  = (float*)(w + OFF_PMAX);
  float* featp = (float*)(w + OFF_FEAT);
  float* ebias = (float*)(w + OFF_EB);
  unsigned short* Csw = (unsigned short*)(w + OFF_CSW);

  k_minmax<<<64, 256, 0, stream>>>(X, pmin, pmax);
  k_setup<<<9, 256, 0, stream>>>(pmin, pmax, wsc, wsh, alp, bbi,
                                 bv, bg, bsp, tay, jac, che, fou, wav,
                                 gns, bet, mxl, featp, ebias, Csw);
  k_main<<<1024, 256, 0, stream>>>(X, Csw, featp, ebias, out);
}

// Round 8
// 30.290 us; speedup vs baseline: 1.7025x; 1.0754x over previous
//
#include <hip/hip_runtime.h>
#include <stdint.h>

#define NB   32768
#define NIN  64
#define NOUT 32
// ws layout (bytes)
#define OFF_PMIN 0          // 64*64*4 = 16384
#define OFF_PMAX 16384      // 16384
#define OFF_CSW  32768      // 2560*32*2 = 163840 (16B aligned)

typedef __bf16 bf16x8 __attribute__((ext_vector_type(8)));
typedef float  f32x4  __attribute__((ext_vector_type(4)));

__device__ __forceinline__ float softplus_f(float x) {
  return fmaxf(x, 0.0f) + log1pf(expf(-fabsf(x)));
}

// ---------------- kernel 1: fused prep ----------------
// blocks 0-63:  per-feature min/max partials (512 rows each)
// blocks 64-71: folded coefficients -> Csw (independent of minmax)
// 40-slot basis per feature (5 bf16x8 groups):
//  g0: bsp0..7 | g1: bsp8..10, x, x^2, x^3, x^4, 1 | g2: cos1..8 | g3: sin1..8 | g4: wav0..3,0*4
// frag unit (bf16x8): ((wv*20 + cc*5 + s)*4 + kgi)*32 + o   for feature i = wv*16+kgi*4+cc.
__global__ __launch_bounds__(256) void k_prep(const float* __restrict__ X,
                                              const float* __restrict__ base_v,
                                              const float* __restrict__ base_g,
                                              const float* __restrict__ bsp,
                                              const float* __restrict__ tay,
                                              const float* __restrict__ jac,
                                              const float* __restrict__ che,
                                              const float* __restrict__ fou,
                                              const float* __restrict__ wav,
                                              const float* __restrict__ gains,
                                              const float* __restrict__ alpha,
                                              const float* __restrict__ beta,
                                              const float* __restrict__ mixl,
                                              float* __restrict__ pmin,
                                              float* __restrict__ pmax,
                                              unsigned short* __restrict__ Csw) {
  int t = threadIdx.x;
  if (blockIdx.x < 64) {
    const float4* X4 = (const float4*)X;
    int g = t & 15, r = t >> 4;
    float4 lo = {3.402823466e38f, 3.402823466e38f, 3.402823466e38f, 3.402823466e38f};
    float4 hi = {-3.402823466e38f, -3.402823466e38f, -3.402823466e38f, -3.402823466e38f};
    int base = blockIdx.x * 8192;  // 512 rows * 16 f4
    #pragma unroll 8
    for (int k = 0; k < 32; ++k) {
      float4 v = X4[base + k * 256 + t];
      lo.x = fminf(lo.x, v.x); lo.y = fminf(lo.y, v.y);
      lo.z = fminf(lo.z, v.z); lo.w = fminf(lo.w, v.w);
      hi.x = fmaxf(hi.x, v.x); hi.y = fmaxf(hi.y, v.y);
      hi.z = fmaxf(hi.z, v.z); hi.w = fmaxf(hi.w, v.w);
    }
    __shared__ float4 slo[16][16], shi[16][16];
    slo[r][g] = lo; shi[r][g] = hi;
    __syncthreads();
    if (t < 64) {
      int gg = t >> 2, c = t & 3;
      float l = 3.402823466e38f, h = -3.402823466e38f;
      #pragma unroll
      for (int rr = 0; rr < 16; ++rr) {
        const float* pl = (const float*)&slo[rr][gg];
        const float* ph = (const float*)&shi[rr][gg];
        l = fminf(l, pl[c]); h = fmaxf(h, ph[c]);
      }
      pmin[blockIdx.x * 64 + t] = l;
      pmax[blockIdx.x * 64 + t] = h;
    }
  } else {
    int o = (blockIdx.x - 64) * 4 + (t >> 6);
    int i = t & 63;
    int p = o * 64 + i;
    float spa = softplus_f(alpha[0]);
    float spb = softplus_f(beta[0]);
    float spg[6];
    #pragma unroll
    for (int f = 0; f < 6; ++f) spg[f] = softplus_f(gains[f]);
    float m[6], mmax = -3.402823466e38f;
    #pragma unroll
    for (int f = 0; f < 6; ++f) { m[f] = mixl[p * 6 + f] * 0.5f; mmax = fmaxf(mmax, m[f]); }
    float es = 0.f;
    #pragma unroll
    for (int f = 0; f < 6; ++f) { m[f] = __expf(m[f] - mmax); es += m[f]; }
    float inv = 1.0f / es;

    float vv = base_v[p];
    float s2 = vv * vv;
    #pragma unroll
    for (int d = 1; d < 64; d <<= 1) s2 += __shfl_xor(s2, d);
    float vn = sqrtf(s2);
    float Wid = spa * base_g[o] * vv / vn;   // identity path: sp(alpha)*W[o,i]

    float wB = spb * spg[0] * m[0] * inv;
    float wT = spb * spg[1] * m[1] * inv;
    float wJ = spb * spg[2] * m[2] * inv;
    float wC = spb * spg[3] * m[3] * inv;
    float wF = spb * spg[4] * m[4] * inv * 0.25f;
    float wW = spb * spg[5] * m[5] * inv;

    float j1 = jac[p * 5 + 1], j2 = jac[p * 5 + 2], j3 = jac[p * 5 + 3], j4 = jac[p * 5 + 4];
    float j0 = jac[p * 5 + 0];
    float c0 = che[p * 5 + 0], c1 = che[p * 5 + 1], c2 = che[p * 5 + 2],
          c3 = che[p * 5 + 3], c4 = che[p * 5 + 4];
    float t0 = tay[p * 4 + 0], t1 = tay[p * 4 + 1], t2 = tay[p * 4 + 2], t3 = tay[p * 4 + 3];

    float slot[40];
    #pragma unroll
    for (int k = 0; k < 11; ++k) slot[k] = wB * bsp[p * 11 + k];
    // monomial folds (verified vs reference recurrences)
    slot[11] = Wid + wT * t1
             + wJ * (1.4142136f * j1 - 0.7619780f * j3)
             + wC * (0.7071068f * c1 - 1.5f * c3);                       // x
    slot[12] = wT * 0.5f * t2
             + wJ * (1.2247449f * j2 - 0.9736894f * j4)
             + wC * (1.1547005f * c2 - 3.5777088f * c4);                 // x^2
    slot[13] = wT * (1.0f / 6.0f) * t3
             + wJ * 0.9797959f * j3
             + wC * 2.0f * c3;                                           // x^3
    slot[14] = wJ * 0.7302967f * j4 + wC * 3.5777088f * c4;              // x^4
    slot[15] = wT * t0
             + wJ * (j0 - 0.3464102f * j2 + 0.1147551f * j4)
             + wC * (c0 - 0.5773503f * c2 + 0.4472136f * c4);            // 1
    #pragma unroll
    for (int k = 0; k < 8; ++k) slot[16 + k] = wF * fou[p * 16 + k];      // cos
    #pragma unroll
    for (int k = 0; k < 8; ++k) slot[24 + k] = wF * fou[p * 16 + 8 + k];  // sin
    #pragma unroll
    for (int k = 0; k < 4; ++k) slot[32 + k] = wW * wav[p * 4 + k];
    slot[36] = 0.f; slot[37] = 0.f; slot[38] = 0.f; slot[39] = 0.f;

    int wv = i >> 4, kgi = (i >> 2) & 3, cc = i & 3;
    bf16x8* CBo = reinterpret_cast<bf16x8*>(Csw);
    #pragma unroll
    for (int s = 0; s < 5; ++s) {
      bf16x8 pk;
      #pragma unroll
      for (int j = 0; j < 8; ++j) pk[j] = (__bf16)slot[s * 8 + j];
      int st = wv * 20 + cc * 5 + s;
      CBo[(st * 4 + kgi) * 32 + o] = pk;
    }
  }
}

// ---------------- 40-slot basis -> 5 A-fragments (all in registers) ----------------
__device__ __forceinline__ void basis40(float x, float4 q0, float4 q1, float4 q2,
                                        bf16x8& A0, bf16x8& A1, bf16x8& A2,
                                        bf16x8& A3, bf16x8& A4) {
  // ---- B-spline, normalized coords: u in [0,8], integer knots ----
  {
    float u = (x - q0.x) * q0.y;
    int ji = (int)u;
    float e0 = (ji == 0) ? 1.f : 0.f;
    float e1 = (ji == 1) ? 1.f : 0.f;
    float e2 = (ji == 2) ? 1.f : 0.f;
    float e3 = (ji == 3) ? 1.f : 0.f;
    float e4 = (ji == 4) ? 1.f : 0.f;
    float e5 = (ji == 5) ? 1.f : 0.f;
    float e6 = (ji == 6) ? 1.f : 0.f;
    float e7 = (ji == 7) ? 1.f : 0.f;
    float d0 = u,       d1 = u - 1.f, d2 = u - 2.f, d3 = u - 3.f, d4 = u - 4.f;
    float d5 = u - 5.f, d6 = u - 6.f, d7 = u - 7.f, d8 = u - 8.f;
    float a2 = -d1 * e0;
    float a3 = d0 * e0 - d2 * e1;
    float a4 = d1 * e1 - d3 * e2;
    float a5 = d2 * e2 - d4 * e3;
    float a6 = d3 * e3 - d5 * e4;
    float a7 = d4 * e4 - d6 * e5;
    float a8 = d5 * e5 - d7 * e6;
    float a9 = d6 * e6 - d8 * e7;
    float a10 = d7 * e7;
    float h0 = 0.5f * d0, h1 = 0.5f * d1, h2 = 0.5f * d2, h3 = 0.5f * d3, h4 = 0.5f * d4;
    float h5 = 0.5f * d5, h6 = 0.5f * d6, h7 = 0.5f * d7, h8 = 0.5f * d8;
    float c1v = -d1 * a2;
    float c2v = d0 * a2 - h2 * a3;
    float c3v = h0 * a3 - h3 * a4;
    float c4v = h1 * a4 - h4 * a5;
    float c5v = h2 * a5 - h5 * a6;
    float c6v = h3 * a6 - h6 * a7;
    float c7v = h4 * a7 - h7 * a8;
    float c8v = h5 * a8 - h8 * a9;
    float c9v = h6 * a9 - d8 * a10;
    float c10v = d7 * a10;
    const float TH = 0.33333333333333f;
    A0[0] = (__bf16)(-d1 * c1v);
    A0[1] = (__bf16)(d0 * c1v - h2 * c2v);
    A0[2] = (__bf16)(h0 * c2v - TH * (d3 * c3v));
    A0[3] = (__bf16)((d0 * c3v - d4 * c4v) * TH);
    A0[4] = (__bf16)((d1 * c4v - d5 * c5v) * TH);
    A0[5] = (__bf16)((d2 * c5v - d6 * c6v) * TH);
    A0[6] = (__bf16)((d3 * c6v - d7 * c7v) * TH);
    A0[7] = (__bf16)((d4 * c7v - d8 * c8v) * TH);
    A1[0] = (__bf16)(TH * (d5 * c8v) - h8 * c9v);
    A1[1] = (__bf16)(h6 * c9v - d8 * c10v);
    A1[2] = (__bf16)(d7 * c10v);
  }
  // ---- monomials x, x^2, x^3, x^4, 1 ----
  {
    float x2 = x * x, x3v = x2 * x, x4v = x2 * x2;
    A1[3] = (__bf16)x;
    A1[4] = (__bf16)x2;
    A1[5] = (__bf16)x3v;
    A1[6] = (__bf16)x4v;
    A1[7] = (__bf16)1.0f;
  }
  // ---- Fourier cos1..8 / sin1..8 (angle-doubling tree) ----
  {
    float s1 = __sinf(x), c1f = __cosf(x);
    float c2f = 2.0f * c1f * c1f - 1.0f, s2f = 2.0f * s1 * c1f;
    float c3f = c2f * c1f - s2f * s1,    s3f = s2f * c1f + c2f * s1;
    float c4f = 2.0f * c2f * c2f - 1.0f, s4f = 2.0f * s2f * c2f;
    float c5f = c4f * c1f - s4f * s1,    s5f = s4f * c1f + c4f * s1;
    float c6f = c4f * c2f - s4f * s2f,   s6f = s4f * c2f + c4f * s2f;
    float c7f = c4f * c3f - s4f * s3f,   s7f = s4f * c3f + c4f * s3f;
    float c8f = 2.0f * c4f * c4f - 1.0f, s8f = 2.0f * s4f * c4f;
    A2[0] = (__bf16)c1f; A2[1] = (__bf16)c2f; A2[2] = (__bf16)c3f; A2[3] = (__bf16)c4f;
    A2[4] = (__bf16)c5f; A2[5] = (__bf16)c6f; A2[6] = (__bf16)c7f; A2[7] = (__bf16)c8f;
    A3[0] = (__bf16)s1;  A3[1] = (__bf16)s2f; A3[2] = (__bf16)s3f; A3[3] = (__bf16)s4f;
    A3[4] = (__bf16)s5f; A3[5] = (__bf16)s6f; A3[6] = (__bf16)s7f; A3[7] = (__bf16)s8f;
  }
  // ---- Wavelet ----
  {
    float u0 = (x - q1.z) * q0.z, u1 = (x - q1.w) * q0.w;
    float u2 = (x - q2.x) * q1.x, u3 = (x - q2.y) * q1.y;
    float s0 = u0 * u0, s1w = u1 * u1, s2w = u2 * u2, s3 = u3 * u3;
    A4[0] = (__bf16)((s0 - 1.0f) * __expf(-0.5f * s0));
    A4[1] = (__bf16)((s1w - 1.0f) * __expf(-0.5f * s1w));
    A4[2] = (__bf16)((s2w - 1.0f) * __expf(-0.5f * s2w));
    A4[3] = (__bf16)((s3 - 1.0f) * __expf(-0.5f * s3));
    A4[4] = (__bf16)0.0f; A4[5] = (__bf16)0.0f;
    A4[6] = (__bf16)0.0f; A4[7] = (__bf16)0.0f;
  }
}

// ---------------- kernel 2: main fused kernel ----------------
// Prelude: per-block final min/max reduce (64 partials, L2-resident) + feature
// params into LDS. Main loop: zero-LDS, dual 16-sample tile, 4-way K-split,
// register A and B fragments. One barrier for the cross-wave K-reduction.
__global__ __launch_bounds__(256, 3) void k_main(const float* __restrict__ X,
                                                 const unsigned short* __restrict__ Csw,
                                                 const float* __restrict__ pmin,
                                                 const float* __restrict__ pmax,
                                                 const float* __restrict__ wscale,
                                                 const float* __restrict__ wshift,
                                                 const float* __restrict__ alpha,
                                                 const float* __restrict__ bias,
                                                 float* __restrict__ out) {
  __shared__ float red[3][1024];
  __shared__ float slo[4][64], shi[4][64];
  __shared__ float featL[64][12];
  __shared__ float ebL[32];

  int t = threadIdx.x;
  int w = t >> 6, lane = t & 63;
  int col = lane & 15, kg = lane >> 4;
  int sbase = blockIdx.x * 32;

  // issue global loads first; they fly under the prelude
  const float4* X4 = (const float4*)X;
  float4 xq0 = X4[(sbase + col) * 16 + w * 4 + kg];
  float4 xq1 = X4[(sbase + 16 + col) * 16 + w * 4 + kg];
  float xr0[4] = {xq0.x, xq0.y, xq0.z, xq0.w};
  float xr1[4] = {xq1.x, xq1.y, xq1.z, xq1.w};

  const bf16x8* CB = reinterpret_cast<const bf16x8*>(Csw);
  const bf16x8* CBw = CB + (size_t)w * 2560 + kg * 32;
  bf16x8 B0, B1, B2, B3, B4, B5, B6, B7, B8, B9;
#define LOADB(cc) do { const bf16x8* p_ = CBw + (size_t)(cc) * 640;            \
    B0 = p_[col];        B1 = p_[col + 16];                                    \
    B2 = p_[128 + col];  B3 = p_[128 + col + 16];                              \
    B4 = p_[256 + col];  B5 = p_[256 + col + 16];                              \
    B6 = p_[384 + col];  B7 = p_[384 + col + 16];                              \
    B8 = p_[512 + col];  B9 = p_[512 + col + 16]; } while (0)
  LOADB(0);

  // ---- prelude: feature params ----
  {
    int f = t & 63, q = t >> 6;
    float lo = 3.402823466e38f, hi = -3.402823466e38f;
    #pragma unroll
    for (int pp = 0; pp < 16; ++pp) {
      int p = q * 16 + pp;
      lo = fminf(lo, pmin[p * 64 + f]);
      hi = fmaxf(hi, pmax[p * 64 + f]);
    }
    slo[q][f] = lo; shi[q][f] = hi;
  }
  __syncthreads();
  if (t < 64) {
    float lo = fminf(fminf(slo[0][t], slo[1][t]), fminf(slo[2][t], slo[3][t]));
    float hi = fmaxf(fmaxf(shi[0][t], shi[1][t]), fmaxf(shi[2][t], shi[3][t]));
    if (hi - lo < 1e-8f) { lo = lo - 0.5f; hi = hi + 0.5f; }
    float d = hi - lo;
    featL[t][0] = lo;
    featL[t][1] = 8.0f / d;
    #pragma unroll
    for (int c = 0; c < 4; ++c) {
      float a = softplus_f(wscale[t * 4 + c]) + 1e-6f;
      featL[t][2 + c] = 1.0f / a;
      featL[t][6 + c] = wshift[t * 4 + c];
    }
    featL[t][10] = 0.f; featL[t][11] = 0.f;
  }
  if (t >= 128 && t < 160) {
    int o = t - 128;
    ebL[o] = softplus_f(alpha[0]) * bias[o];
  }
  __syncthreads();

  f32x4 acc00 = {0.f, 0.f, 0.f, 0.f};
  f32x4 acc01 = {0.f, 0.f, 0.f, 0.f};
  f32x4 acc10 = {0.f, 0.f, 0.f, 0.f};
  f32x4 acc11 = {0.f, 0.f, 0.f, 0.f};

  #pragma unroll 1
  for (int c = 0; c < 4; ++c) {
    int f = w * 16 + kg * 4 + c;
    const float4* fq = (const float4*)&featL[f][0];
    float4 q0 = fq[0];   // xmin, ih, inva0, inva1
    float4 q1 = fq[1];   // inva2, inva3, shift0, shift1
    float4 q2 = fq[2];   // shift2, shift3, -, -

    bf16x8 A0, A1, A2, A3, A4;

    // tile 0
    basis40(xr0[c], q0, q1, q2, A0, A1, A2, A3, A4);
    acc00 = __builtin_amdgcn_mfma_f32_16x16x32_bf16(A0, B0, acc00, 0, 0, 0);
    acc01 = __builtin_amdgcn_mfma_f32_16x16x32_bf16(A0, B1, acc01, 0, 0, 0);
    acc00 = __builtin_amdgcn_mfma_f32_16x16x32_bf16(A1, B2, acc00, 0, 0, 0);
    acc01 = __builtin_amdgcn_mfma_f32_16x16x32_bf16(A1, B3, acc01, 0, 0, 0);
    acc00 = __builtin_amdgcn_mfma_f32_16x16x32_bf16(A2, B4, acc00, 0, 0, 0);
    acc01 = __builtin_amdgcn_mfma_f32_16x16x32_bf16(A2, B5, acc01, 0, 0, 0);
    acc00 = __builtin_amdgcn_mfma_f32_16x16x32_bf16(A3, B6, acc00, 0, 0, 0);
    acc01 = __builtin_amdgcn_mfma_f32_16x16x32_bf16(A3, B7, acc01, 0, 0, 0);
    acc00 = __builtin_amdgcn_mfma_f32_16x16x32_bf16(A4, B8, acc00, 0, 0, 0);
    acc01 = __builtin_amdgcn_mfma_f32_16x16x32_bf16(A4, B9, acc01, 0, 0, 0);

    // tile 1 (same B fragments)
    basis40(xr1[c], q0, q1, q2, A0, A1, A2, A3, A4);
    acc10 = __builtin_amdgcn_mfma_f32_16x16x32_bf16(A0, B0, acc10, 0, 0, 0);
    acc11 = __builtin_amdgcn_mfma_f32_16x16x32_bf16(A0, B1, acc11, 0, 0, 0);
    acc10 = __builtin_amdgcn_mfma_f32_16x16x32_bf16(A1, B2, acc10, 0, 0, 0);
    acc11 = __builtin_amdgcn_mfma_f32_16x16x32_bf16(A1, B3, acc11, 0, 0, 0);
    acc10 = __builtin_amdgcn_mfma_f32_16x16x32_bf16(A2, B4, acc10, 0, 0, 0);
    acc11 = __builtin_amdgcn_mfma_f32_16x16x32_bf16(A2, B5, acc11, 0, 0, 0);
    acc10 = __builtin_amdgcn_mfma_f32_16x16x32_bf16(A3, B6, acc10, 0, 0, 0);
    acc11 = __builtin_amdgcn_mfma_f32_16x16x32_bf16(A3, B7, acc11, 0, 0, 0);
    acc10 = __builtin_amdgcn_mfma_f32_16x16x32_bf16(A4, B8, acc10, 0, 0, 0);
    acc11 = __builtin_amdgcn_mfma_f32_16x16x32_bf16(A4, B9, acc11, 0, 0, 0);

    if (c < 3) LOADB(c + 1);   // hides under next pass's basis compute
  }
#undef LOADB

  // ---- 4-way cross-wave K-reduction (single barrier) ----
  if (w > 0) {
    float* rw = &red[w - 1][0];
    #pragma unroll
    for (int j = 0; j < 4; ++j) {
      int idx = (kg * 4 + j) * 32 + col;
      rw[idx]            = acc00[j];
      rw[idx + 16]       = acc01[j];
      rw[512 + idx]      = acc10[j];
      rw[512 + idx + 16] = acc11[j];
    }
  }
  __syncthreads();
  if (w == 0) {
    float eb0 = ebL[col], eb1 = ebL[col + 16];
    #pragma unroll
    for (int j = 0; j < 4; ++j) {
      int idx0 = (kg * 4 + j) * 32 + col;
      int idx1 = idx0 + 16;
      int row0 = sbase + kg * 4 + j;
      int row1 = row0 + 16;
      out[row0 * 32 + col]      = acc00[j] + red[0][idx0] + red[1][idx0] + red[2][idx0] + eb0;
      out[row0 * 32 + col + 16] = acc01[j] + red[0][idx1] + red[1][idx1] + red[2][idx1] + eb1;
      out[row1 * 32 + col]      = acc10[j] + red[0][512 + idx0] + red[1][512 + idx0] + red[2][512 + idx0] + eb0;
      out[row1 * 32 + col + 16] = acc11[j] + red[0][512 + idx1] + red[1][512 + idx1] + red[2][512 + idx1] + eb1;
    }
  }
}

extern "C" void kernel_launch(void* const* d_in, const int* in_sizes, int n_in,
                              void* d_out, int out_size, void* d_ws, size_t ws_size,
                              hipStream_t stream) {
  const float* X   = (const float*)d_in[0];
  const float* bv  = (const float*)d_in[1];
  const float* bg  = (const float*)d_in[2];
  const float* bbi = (const float*)d_in[3];
  const float* bsp = (const float*)d_in[4];
  const float* tay = (const float*)d_in[5];
  const float* jac = (const float*)d_in[6];
  const float* che = (const float*)d_in[7];
  const float* fou = (const float*)d_in[8];
  const float* wav = (const float*)d_in[9];
  const float* wsc = (const float*)d_in[10];
  const float* wsh = (const float*)d_in[11];
  const float* gns = (const float*)d_in[12];
  const float* alp = (const float*)d_in[13];
  const float* bet = (const float*)d_in[14];
  const float* mxl = (const float*)d_in[15];
  float* out = (float*)d_out;

  uint8_t* w = (uint8_t*)d_ws;
  float* pmin = (float*)(w + OFF_PMIN);
  float* pmax = (float*)(w + OFF_PMAX);
  unsigned short* Csw = (unsigned short*)(w + OFF_CSW);

  k_prep<<<72, 256, 0, stream>>>(X, bv, bg, bsp, tay, jac, che, fou, wav,
                                 gns, alp, bet, mxl, pmin, pmax, Csw);
  k_main<<<1024, 256, 0, stream>>>(X, Csw, pmin, pmax, wsc, wsh, alp, bbi, out);
}